// Round 13
// baseline (254.688 us; speedup 1.0000x reference)
//
#include <hip/hip_runtime.h>
#include <hip/hip_bf16.h>

#define NA 50000
#define NP 1000000
#define FA 75
#define FP 14
#define H  50

typedef __attribute__((ext_vector_type(8))) short short8;
typedef __attribute__((ext_vector_type(4))) float f32x4;
typedef __attribute__((ext_vector_type(2))) float f32x2;

__device__ __forceinline__ ushort f2bf(float f) {
    union { float f; unsigned u; } v; v.f = f;
    unsigned r = v.u + 0x7FFF + ((v.u >> 16) & 1);   // RNE
    return (ushort)(r >> 16);
}
__device__ __forceinline__ unsigned cvtpk(float lo, float hi) {
    unsigned r;
    asm("v_cvt_pk_bf16_f32 %0, %1, %2" : "=v"(r) : "v"(lo), "v"(hi));
    return r;
}
__device__ __forceinline__ ushort f2bf1(float f) { return (ushort)cvtpk(f, f); }
__device__ __forceinline__ unsigned pk_fp8(float u, float v) {
    unsigned r;
    asm("v_cvt_pk_fp8_f32 %0, %1, %2" : "=v"(r) : "v"(u), "v"(v));
    return r;
}
__device__ __forceinline__ float2 unpk_fp8(unsigned w) {
    float2 r;
    asm("v_cvt_pk_f32_fp8 %0, %1" : "=v"(r) : "v"(w));
    return r;
}
__device__ __forceinline__ short8 mk8(unsigned a, unsigned b, unsigned c, unsigned d) {
    union { unsigned u[4]; short8 s; } x; x.u[0]=a; x.u[1]=b; x.u[2]=c; x.u[3]=d; return x.s;
}

// ---------------------------------------------------------------------------
// K0: pack weights into MFMA B-fragment order (bf16), zero-padded.
// B-frag 16x16x32: lane l, elem j -> W[k = tk*32+(l>>4)*8+j][col = tn*16+(l&15)]
// WPf/WAf:  [tk=4][tn=4][64][8]   (K=128 pad from 100, N=64 pad from 50)
// W2f:      [tn=8][64][8]         (K=32 pad from 14; tn 0..3 = W_PP, 4..7 = W_PA)
// WPREf:    [tk=3][tn=12][64][8]  (K=96 pad from 75; N=192: [AA|pad][U|pad][V|pad])
// ---------------------------------------------------------------------------
__global__ __launch_bounds__(256) void k_prep_frags(
    const float* __restrict__ W_P, const float* __restrict__ W_A,
    const float* __restrict__ W_PP, const float* __restrict__ W_PA,
    const float* __restrict__ W_AA, const float* __restrict__ W_AP,
    ushort* __restrict__ WPf, ushort* __restrict__ WAf, ushort* __restrict__ W2f,
    ushort* __restrict__ WPREf)
{
    const int t0 = blockIdx.x * 256 + threadIdx.x;
    const int STR = 16 * 256;
    for (int idx = t0; idx < 4*4*64*8; idx += STR) {
        int j = idx & 7, l = (idx >> 3) & 63, tn = (idx >> 9) & 3, tk = idx >> 11;
        int k = tk*32 + (l>>4)*8 + j;
        int c = tn*16 + (l&15);
        ushort vp = 0, va = 0;
        if (k < 100 && c < 50) { vp = f2bf(W_P[k*50+c]); va = f2bf(W_A[k*50+c]); }
        WPf[idx] = vp; WAf[idx] = va;
    }
    for (int idx = t0; idx < 8*64*8; idx += STR) {
        int j = idx & 7, l = (idx >> 3) & 63, tn = idx >> 9;
        int k = (l>>4)*8 + j;
        int c = (tn&3)*16 + (l&15);
        ushort v = 0;
        if (k < 14 && c < 50) v = f2bf(tn < 4 ? W_PP[k*50+c] : W_PA[k*50+c]);
        W2f[idx] = v;
    }
    for (int idx = t0; idx < 3*12*64*8; idx += STR) {
        int j = idx & 7, l = (idx >> 3) & 63;
        int g = idx >> 9;            // tk*12+tn
        int tn = g % 12, tk = g / 12;
        int k = tk*32 + (l>>4)*8 + j;
        int sn = tn*16 + (l&15);
        int which = sn >> 6, col = sn & 63;
        ushort v = 0;
        if (k < FA && col < H) {
            float w = (which == 0) ? W_AA[k*H+col]
                    : (which == 1) ? W_AP[k*H+col]
                                   : W_AP[(FA+k)*H+col];
            v = f2bf(w);
        }
        WPREf[idx] = v;
    }
}

// ---------------------------------------------------------------------------
// K1: per-atom precompute via MFMA, 64 atoms/block.
//   AAb bf16 [NA][50];  UV8[atom][64] ushort: byte0=fp8(U), byte1=fp8(V).
//   af read via non-temporal loads (streaming, no L2 allocate).
// ---------------------------------------------------------------------------
__global__ __launch_bounds__(256) void k_atom_pre(
    const float* __restrict__ af, const ushort* __restrict__ WPREf,
    const float* __restrict__ b_AA,
    ushort* __restrict__ AAb, ushort* __restrict__ UV8)
{
    __shared__ __align__(16) ushort sAF[64][104];
    const int t = threadIdx.x, lane = t & 63, w = t >> 6;
    const int a0 = blockIdx.x * 64, row0 = w * 16;

    for (int idx = t; idx < 64*96; idx += 256) {
        int r = idx / 96, c = idx % 96;
        int ag = a0 + r;
        float v = (c < FA && ag < NA) ? __builtin_nontemporal_load(&af[(size_t)ag*FA + c]) : 0.f;
        sAF[r][c] = f2bf(v);
    }
    __syncthreads();

    short8 afr[3];
    #pragma unroll
    for (int tk = 0; tk < 3; ++tk)
        afr[tk] = *(const short8*)&sAF[row0 + (lane&15)][tk*32 + (lane>>4)*8];

    const short8* B = (const short8*)WPREf;
    f32x4 acc[12];
    #pragma unroll
    for (int tn = 0; tn < 12; ++tn) acc[tn] = (f32x4){0.f, 0.f, 0.f, 0.f};
    #pragma unroll
    for (int tk = 0; tk < 3; ++tk) {
        #pragma unroll
        for (int tn = 0; tn < 12; ++tn) {
            short8 b = B[(tk*12 + tn)*64 + lane];
            acc[tn] = __builtin_amdgcn_mfma_f32_16x16x32_bf16(afr[tk], b, acc[tn], 0, 0, 0);
        }
    }

    #pragma unroll
    for (int tn = 0; tn < 4; ++tn) {
        int col = tn*16 + (lane&15);
        if (col < H) {
            float ba = b_AA[col];
            #pragma unroll
            for (int reg = 0; reg < 4; ++reg) {
                int atom = a0 + row0 + (lane>>4)*4 + reg;
                if (atom < NA) {
                    AAb[(size_t)atom*H + col] = f2bf(fmaxf(acc[tn][reg] + ba, 0.f));
                    UV8[(size_t)atom*64 + col] =
                        (ushort)pk_fp8(acc[4 + tn][reg], acc[8 + tn][reg]);
                }
            }
        }
    }
}

// ---------------------------------------------------------------------------
// K2: 64 pairs/block, 4 waves (r9 structure) + CACHE-POLLUTION CONTROL.
//   pf via non-temporal loads, Pout via non-temporal stores (no L2 allocate)
//   so the 4MB/XCD L2 holds only UV8 (6.4MB hot set) + weight frags.
//   fp8 UV8 gather burst split in two groups, counted vmcnt waits.
// ---------------------------------------------------------------------------
__global__ __launch_bounds__(256, 4) void k_pairs(
    const float* __restrict__ pf, const int* __restrict__ seg, const int* __restrict__ a2p,
    const ushort* __restrict__ UV8,
    const float* __restrict__ b_PP, const float* __restrict__ b_PA,
    const float* __restrict__ b_AP, const float* __restrict__ b_P,
    const ushort* __restrict__ WPf, const ushort* __restrict__ W2f,
    float* __restrict__ PAsum, float* __restrict__ Pout)
{
    __shared__ __align__(16) ushort sX[64][136];    // X bf16: [APs|PP|0pad], K=128

    const int t = threadIdx.x;
    const int w = t >> 6, lane = t & 63;
    const int q = lane >> 4, m = lane & 15;
    const int p0 = blockIdx.x * 64;
    const int row0 = w * 16;
    const int p0w_u = __builtin_amdgcn_readfirstlane(p0 + row0);  // uniform

    // ---- scalar loads: pair indices + segment ids for this wave's 16 pairs ----
    const int* a2ps = a2p + 2 * p0w_u;
    const int* segs = seg + p0w_u;
    int pi[16], pj[16], sg[16];
    #pragma unroll
    for (int it = 0; it < 16; ++it) {
        pi[it] = a2ps[2*it];
        pj[it] = a2ps[2*it + 1];
        sg[it] = segs[it];
    }

    // ---- compiler-tracked loads FIRST (pf nt, bap), pinned above the burst ----
    const f32x2* pf2 = (const f32x2*)(pf + (size_t)(p0w_u + m) * FP);
    f32x2 g0 = {0.f,0.f}, g1 = {0.f,0.f}, g2 = {0.f,0.f}, g3 = {0.f,0.f};
    if (q == 0) {
        g0 = __builtin_nontemporal_load(&pf2[0]);
        g1 = __builtin_nontemporal_load(&pf2[1]);
        g2 = __builtin_nontemporal_load(&pf2[2]);
        g3 = __builtin_nontemporal_load(&pf2[3]);
    } else if (q == 1) {
        g0 = __builtin_nontemporal_load(&pf2[4]);
        g1 = __builtin_nontemporal_load(&pf2[5]);
        g2 = __builtin_nontemporal_load(&pf2[6]);
    }
    float bap = (lane < H) ? b_AP[lane] : 0.f;
    __builtin_amdgcn_sched_barrier(0);   // pin the above loads before the burst

    // ---- UV8 gather burst: 2 groups of 16 volatile ushort loads ----
    unsigned uvi[16], uvj[16];
    const unsigned lo2 = (unsigned)(lane << 1);
    #pragma unroll
    for (int it = 0; it < 8; ++it) {                 // group A
        unsigned offi = ((unsigned)pi[it] << 7) | lo2;
        unsigned offj = ((unsigned)pj[it] << 7) | lo2;
        asm volatile("global_load_ushort %0, %1, %2"
                     : "=v"(uvi[it]) : "v"(offi), "s"(UV8));
        asm volatile("global_load_ushort %0, %1, %2"
                     : "=v"(uvj[it]) : "v"(offj), "s"(UV8));
    }
    #pragma unroll
    for (int it = 8; it < 16; ++it) {                // group B
        unsigned offi = ((unsigned)pi[it] << 7) | lo2;
        unsigned offj = ((unsigned)pj[it] << 7) | lo2;
        asm volatile("global_load_ushort %0, %1, %2"
                     : "=v"(uvi[it]) : "v"(offi), "s"(UV8));
        asm volatile("global_load_ushort %0, %1, %2"
                     : "=v"(uvj[it]) : "v"(offj), "s"(UV8));
    }

    // zero X K-pad cols 100..127 of own rows (overlaps with loads in flight)
    if (lane < 16) {
        unsigned long long* rowp = (unsigned long long*)&sX[row0 + lane][100];
        #pragma unroll
        for (int d = 0; d < 7; ++d) rowp[d] = 0ull;
    }

    // group A ready (<=16 outstanding = group B); consume rows 0..7
    asm volatile("s_waitcnt vmcnt(16)" ::: "memory");
    __builtin_amdgcn_sched_barrier(0);
    #pragma unroll
    for (int it = 0; it < 8; ++it) {
        if (lane < H) {
            float2 fi = unpk_fp8(uvi[it]);   // x=U_i, y=V_i
            float2 fj = unpk_fp8(uvj[it]);   // x=U_j, y=V_j
            float aps = fmaxf(fi.x + fj.y + bap, 0.f) + fmaxf(fj.x + fi.y + bap, 0.f);
            sX[row0 + it][lane] = f2bf1(aps);
        }
    }
    // full drain; consume rows 8..15
    asm volatile("s_waitcnt vmcnt(0)" ::: "memory");
    __builtin_amdgcn_sched_barrier(0);
    #pragma unroll
    for (int it = 8; it < 16; ++it) {
        if (lane < H) {
            float2 fi = unpk_fp8(uvi[it]);
            float2 fj = unpk_fp8(uvj[it]);
            float aps = fmaxf(fi.x + fj.y + bap, 0.f) + fmaxf(fj.x + fi.y + bap, 0.f);
            sX[row0 + it][lane] = f2bf1(aps);
        }
    }

    // ---- PP -> sX[:,50:100] (bf16), PA -> regs, one K=32 MFMA pass ----
    short8 afrag = mk8(cvtpk(g0.x, g0.y), cvtpk(g1.x, g1.y),
                       cvtpk(g2.x, g2.y), cvtpk(g3.x, g3.y));
    float pa[4][4];
    {
        const short8* B = (const short8*)W2f;
        #pragma unroll
        for (int tn = 0; tn < 8; ++tn) {
            f32x4 c = {0.f, 0.f, 0.f, 0.f};
            short8 b = B[tn*64 + lane];
            c = __builtin_amdgcn_mfma_f32_16x16x32_bf16(afrag, b, c, 0, 0, 0);
            int col = (tn&3)*16 + m;
            if (tn < 4) {
                if (col < H) {
                    float bias = b_PP[col];
                    #pragma unroll
                    for (int reg = 0; reg < 4; ++reg)
                        sX[row0 + q*4 + reg][H + col] = f2bf1(fmaxf(c[reg] + bias, 0.f));
                }
            } else {
                float bias = (col < H) ? b_PA[col] : 0.f;
                #pragma unroll
                for (int reg = 0; reg < 4; ++reg)
                    pa[tn-4][reg] = fmaxf(c[reg] + bias, 0.f);
            }
        }
    }

    // ---- wave-level 16-row segment-sum of PA (seg sorted) ----
    #pragma unroll
    for (int tn4 = 0; tn4 < 4; ++tn4) {
        float v[16];
        #pragma unroll
        for (int g = 0; g < 4; ++g) {
            int src = m + (g << 4);
            #pragma unroll
            for (int r4 = 0; r4 < 4; ++r4)
                v[g*4 + r4] = __shfl(pa[tn4][r4], src, 64);
        }
        int col = tn4*16 + m;
        if (q == 0 && col < H) {
            float acc = v[0]; int cur = sg[0];
            #pragma unroll
            for (int r = 1; r < 16; ++r) {
                if (sg[r] != cur) {
                    atomicAdd(&PAsum[(size_t)cur*H + col], acc);
                    acc = 0.f; cur = sg[r];
                }
                acc += v[r];
            }
            atomicAdd(&PAsum[(size_t)cur*H + col], acc);
        }
    }

    // all wave-local LDS writes must land before fragment reads (wave-sync)
    asm volatile("s_waitcnt lgkmcnt(0)" ::: "memory");
    __builtin_amdgcn_sched_barrier(0);

    // ---- P = relu(X @ W_P + b_P), per-wave M=16 N=64 K=128; nt stores ----
    {
        short8 afr[4];
        #pragma unroll
        for (int tk = 0; tk < 4; ++tk)
            afr[tk] = *(const short8*)&sX[row0 + m][tk*32 + q*8];
        const short8* B = (const short8*)WPf;
        f32x4 acc[4];
        #pragma unroll
        for (int tn = 0; tn < 4; ++tn) acc[tn] = (f32x4){0.f, 0.f, 0.f, 0.f};
        #pragma unroll
        for (int tk = 0; tk < 4; ++tk) {
            #pragma unroll
            for (int tn = 0; tn < 4; ++tn) {
                short8 b = B[(tk*4 + tn)*64 + lane];
                acc[tn] = __builtin_amdgcn_mfma_f32_16x16x32_bf16(afr[tk], b, acc[tn], 0, 0, 0);
            }
        }
        #pragma unroll
        for (int tn = 0; tn < 4; ++tn) {
            int col = tn*16 + m;
            if (col < H) {
                float bp = b_P[col];
                #pragma unroll
                for (int reg = 0; reg < 4; ++reg) {
                    int row = row0 + q*4 + reg;
                    __builtin_nontemporal_store(fmaxf(acc[tn][reg] + bp, 0.f),
                                                &Pout[(size_t)(p0 + row)*H + col]);
                }
            }
        }
    }
}

// ---------------------------------------------------------------------------
// K3: A = relu([AAb | PAsum] @ W_A + b_A), 64 atoms/block; nt streaming I/O.
// ---------------------------------------------------------------------------
__global__ __launch_bounds__(256) void k_A(
    const ushort* __restrict__ AAb, const float* __restrict__ PAsum,
    const ushort* __restrict__ WAf, const float* __restrict__ b_A,
    float* __restrict__ Aout)
{
    __shared__ __align__(16) ushort sX[64][136];
    const int t = threadIdx.x, lane = t & 63, w = t >> 6;
    const int a0 = blockIdx.x * 64;
    const int row0 = w * 16;

    for (int idx = t; idx < 64*50; idx += 256) {
        int r = idx / 50, c = idx % 50;
        int rg = a0 + r;
        ushort aa = 0; float ps = 0.f;
        if (rg < NA) {
            aa = __builtin_nontemporal_load(&AAb[(size_t)rg*H + c]);
            ps = __builtin_nontemporal_load(&PAsum[(size_t)rg*H + c]);
        }
        sX[r][c] = aa;
        sX[r][H + c] = f2bf1(ps);
    }
    for (int idx = t; idx < 64*28; idx += 256) {
        int r = idx / 28, c = 100 + idx % 28;
        sX[r][c] = 0;
    }
    __syncthreads();

    short8 afr[4];
    #pragma unroll
    for (int tk = 0; tk < 4; ++tk)
        afr[tk] = *(const short8*)&sX[row0 + (lane&15)][tk*32 + (lane>>4)*8];
    const short8* B = (const short8*)WAf;
    f32x4 acc[4];
    #pragma unroll
    for (int tn = 0; tn < 4; ++tn) acc[tn] = (f32x4){0.f, 0.f, 0.f, 0.f};
    #pragma unroll
    for (int tk = 0; tk < 4; ++tk) {
        #pragma unroll
        for (int tn = 0; tn < 4; ++tn) {
            short8 b = B[(tk*4 + tn)*64 + lane];
            acc[tn] = __builtin_amdgcn_mfma_f32_16x16x32_bf16(afr[tk], b, acc[tn], 0, 0, 0);
        }
    }
    #pragma unroll
    for (int tn = 0; tn < 4; ++tn) {
        int col = tn*16 + (lane&15);
        if (col < H) {
            float ba = b_A[col];
            #pragma unroll
            for (int reg = 0; reg < 4; ++reg) {
                int row = row0 + (lane>>4)*4 + reg;
                int rg = a0 + row;
                if (rg < NA)
                    __builtin_nontemporal_store(fmaxf(acc[tn][reg] + ba, 0.f),
                                                &Aout[(size_t)rg*H + col]);
            }
        }
    }
}

// ---------------------------------------------------------------------------
extern "C" void kernel_launch(void* const* d_in, const int* in_sizes, int n_in,
                              void* d_out, int out_size, void* d_ws, size_t ws_size,
                              hipStream_t stream)
{
    const float* af   = (const float*)d_in[0];
    const float* pf   = (const float*)d_in[1];
    const int*   seg  = (const int*)d_in[2];
    const int*   a2p  = (const int*)d_in[3];
    const float* W_AA = (const float*)d_in[4];
    const float* b_AA = (const float*)d_in[5];
    const float* W_PA = (const float*)d_in[6];
    const float* b_PA = (const float*)d_in[7];
    const float* W_A  = (const float*)d_in[8];
    const float* b_A  = (const float*)d_in[9];
    const float* W_AP = (const float*)d_in[10];
    const float* b_AP = (const float*)d_in[11];
    const float* W_PP = (const float*)d_in[12];
    const float* b_PP = (const float*)d_in[13];
    const float* W_P  = (const float*)d_in[14];
    const float* b_P  = (const float*)d_in[15];

    float* Aout = (float*)d_out;
    float* Pout = (float*)d_out + (size_t)NA * H;

    ushort*   AAb   = (ushort*)d_ws;                         // 5 MB
    float*    PAsum = (float*)(AAb + (size_t)NA * H);        // 10 MB
    ushort*   UV8   = (ushort*)(PAsum + (size_t)NA * H);     // 6.4 MB
    ushort*   WPf   = UV8 + (size_t)NA * 64;                 // 16 KB
    ushort*   WAf   = WPf + 4*4*64*8;                        // 16 KB
    ushort*   W2f   = WAf + 4*4*64*8;                        // 8 KB
    ushort*   WPREf = W2f + 8*64*8;                          // 36 KB

    hipMemsetAsync(PAsum, 0, (size_t)NA * H * sizeof(float), stream);
    k_prep_frags<<<16, 256, 0, stream>>>(W_P, W_A, W_PP, W_PA, W_AA, W_AP,
                                         WPf, WAf, W2f, WPREf);
    k_atom_pre<<<(NA + 63) / 64, 256, 0, stream>>>(af, WPREf, b_AA, AAb, UV8);
    k_pairs<<<NP / 64, 256, 0, stream>>>(pf, seg, a2p, UV8, b_PP, b_PA, b_AP, b_P,
                                         WPf, W2f, PAsum, Pout);
    k_A<<<(NA + 63) / 64, 256, 0, stream>>>(AAb, PAsum, WAf, b_A, Aout);
}

// Round 14
// 225.547 us; speedup vs baseline: 1.1292x; 1.1292x over previous
//
#include <hip/hip_runtime.h>
#include <hip/hip_bf16.h>

#define NA 50000
#define NP 1000000
#define FA 75
#define FP 14
#define H  50

typedef __attribute__((ext_vector_type(8))) short short8;
typedef __attribute__((ext_vector_type(4))) float f32x4;
typedef __attribute__((ext_vector_type(2))) float f32x2;

__device__ __forceinline__ ushort f2bf(float f) {
    union { float f; unsigned u; } v; v.f = f;
    unsigned r = v.u + 0x7FFF + ((v.u >> 16) & 1);   // RNE
    return (ushort)(r >> 16);
}
__device__ __forceinline__ unsigned cvtpk(float lo, float hi) {
    unsigned r;
    asm("v_cvt_pk_bf16_f32 %0, %1, %2" : "=v"(r) : "v"(lo), "v"(hi));
    return r;
}
__device__ __forceinline__ ushort f2bf1(float f) { return (ushort)cvtpk(f, f); }
__device__ __forceinline__ unsigned pk_fp8(float u, float v) {
    unsigned r;
    asm("v_cvt_pk_fp8_f32 %0, %1, %2" : "=v"(r) : "v"(u), "v"(v));
    return r;
}
__device__ __forceinline__ float2 unpk_fp8(unsigned w) {
    float2 r;
    asm("v_cvt_pk_f32_fp8 %0, %1" : "=v"(r) : "v"(w));
    return r;
}
__device__ __forceinline__ short8 mk8(unsigned a, unsigned b, unsigned c, unsigned d) {
    union { unsigned u[4]; short8 s; } x; x.u[0]=a; x.u[1]=b; x.u[2]=c; x.u[3]=d; return x.s;
}

// ---------------------------------------------------------------------------
// K0: pack weights into MFMA B-fragment order (bf16), zero-padded.
// ---------------------------------------------------------------------------
__global__ __launch_bounds__(256) void k_prep_frags(
    const float* __restrict__ W_P, const float* __restrict__ W_A,
    const float* __restrict__ W_PP, const float* __restrict__ W_PA,
    const float* __restrict__ W_AA, const float* __restrict__ W_AP,
    ushort* __restrict__ WPf, ushort* __restrict__ WAf, ushort* __restrict__ W2f,
    ushort* __restrict__ WPREf)
{
    const int t0 = blockIdx.x * 256 + threadIdx.x;
    const int STR = 16 * 256;
    for (int idx = t0; idx < 4*4*64*8; idx += STR) {
        int j = idx & 7, l = (idx >> 3) & 63, tn = (idx >> 9) & 3, tk = idx >> 11;
        int k = tk*32 + (l>>4)*8 + j;
        int c = tn*16 + (l&15);
        ushort vp = 0, va = 0;
        if (k < 100 && c < 50) { vp = f2bf(W_P[k*50+c]); va = f2bf(W_A[k*50+c]); }
        WPf[idx] = vp; WAf[idx] = va;
    }
    for (int idx = t0; idx < 8*64*8; idx += STR) {
        int j = idx & 7, l = (idx >> 3) & 63, tn = idx >> 9;
        int k = (l>>4)*8 + j;
        int c = (tn&3)*16 + (l&15);
        ushort v = 0;
        if (k < 14 && c < 50) v = f2bf(tn < 4 ? W_PP[k*50+c] : W_PA[k*50+c]);
        W2f[idx] = v;
    }
    for (int idx = t0; idx < 3*12*64*8; idx += STR) {
        int j = idx & 7, l = (idx >> 3) & 63;
        int g = idx >> 9;            // tk*12+tn
        int tn = g % 12, tk = g / 12;
        int k = tk*32 + (l>>4)*8 + j;
        int sn = tn*16 + (l&15);
        int which = sn >> 6, col = sn & 63;
        ushort v = 0;
        if (k < FA && col < H) {
            float w = (which == 0) ? W_AA[k*H+col]
                    : (which == 1) ? W_AP[k*H+col]
                                   : W_AP[(FA+k)*H+col];
            v = f2bf(w);
        }
        WPREf[idx] = v;
    }
}

// ---------------------------------------------------------------------------
// K1: per-atom precompute via MFMA, 64 atoms/block.
//   AAb bf16 [NA][50];  UV8[atom][64] ushort: byte0=fp8(U), byte1=fp8(V).
// ---------------------------------------------------------------------------
__global__ __launch_bounds__(256) void k_atom_pre(
    const float* __restrict__ af, const ushort* __restrict__ WPREf,
    const float* __restrict__ b_AA,
    ushort* __restrict__ AAb, ushort* __restrict__ UV8)
{
    __shared__ __align__(16) ushort sAF[64][104];
    const int t = threadIdx.x, lane = t & 63, w = t >> 6;
    const int a0 = blockIdx.x * 64, row0 = w * 16;

    for (int idx = t; idx < 64*96; idx += 256) {
        int r = idx / 96, c = idx % 96;
        int ag = a0 + r;
        float v = (c < FA && ag < NA) ? __builtin_nontemporal_load(&af[(size_t)ag*FA + c]) : 0.f;
        sAF[r][c] = f2bf(v);
    }
    __syncthreads();

    short8 afr[3];
    #pragma unroll
    for (int tk = 0; tk < 3; ++tk)
        afr[tk] = *(const short8*)&sAF[row0 + (lane&15)][tk*32 + (lane>>4)*8];

    const short8* B = (const short8*)WPREf;
    f32x4 acc[12];
    #pragma unroll
    for (int tn = 0; tn < 12; ++tn) acc[tn] = (f32x4){0.f, 0.f, 0.f, 0.f};
    #pragma unroll
    for (int tk = 0; tk < 3; ++tk) {
        #pragma unroll
        for (int tn = 0; tn < 12; ++tn) {
            short8 b = B[(tk*12 + tn)*64 + lane];
            acc[tn] = __builtin_amdgcn_mfma_f32_16x16x32_bf16(afr[tk], b, acc[tn], 0, 0, 0);
        }
    }

    #pragma unroll
    for (int tn = 0; tn < 4; ++tn) {
        int col = tn*16 + (lane&15);
        if (col < H) {
            float ba = b_AA[col];
            #pragma unroll
            for (int reg = 0; reg < 4; ++reg) {
                int atom = a0 + row0 + (lane>>4)*4 + reg;
                if (atom < NA) {
                    AAb[(size_t)atom*H + col] = f2bf(fmaxf(acc[tn][reg] + ba, 0.f));
                    UV8[(size_t)atom*64 + col] =
                        (ushort)pk_fp8(acc[4 + tn][reg], acc[8 + tn][reg]);
                }
            }
        }
    }
}

// ---------------------------------------------------------------------------
// K2: 32 PAIRS PER WAVE (2 sequential strips of 16), 128 pairs/block, 4 waves.
//   Grid 7813, wave-early-exit (no barriers in kernel). Per-strip body is the
//   proven r9 structure: fp8 gather burst (asm, one vmcnt), PP via K=32 MFMA,
//   PA reg segsum, P via 16 MFMA. Halves wave count -> amortizes per-wave
//   fixed latency (scalar idx chain, launch/drain, gather round-trip).
// ---------------------------------------------------------------------------
__global__ __launch_bounds__(256, 4) void k_pairs(
    const float* __restrict__ pf, const int* __restrict__ seg, const int* __restrict__ a2p,
    const ushort* __restrict__ UV8,
    const float* __restrict__ b_PP, const float* __restrict__ b_PA,
    const float* __restrict__ b_AP, const float* __restrict__ b_P,
    const ushort* __restrict__ WPf, const ushort* __restrict__ W2f,
    float* __restrict__ PAsum, float* __restrict__ Pout)
{
    __shared__ __align__(16) ushort sX[64][136];    // X bf16: [APs|PP|0pad], K=128

    const int t = threadIdx.x;
    const int w = t >> 6, lane = t & 63;
    const int q = lane >> 4, m = lane & 15;
    const int row0 = w * 16;
    const int base = blockIdx.x * 128 + w * 32;
    if (base >= NP) return;                          // tail waves (no barriers)

    float bap = (lane < H) ? b_AP[lane] : 0.f;

    // zero X K-pad cols 100..127 of own rows (once; strips reuse rows)
    if (lane < 16) {
        unsigned long long* rowp = (unsigned long long*)&sX[row0 + lane][100];
        #pragma unroll
        for (int d = 0; d < 7; ++d) rowp[d] = 0ull;
    }

    for (int s = 0; s < 2; ++s) {
        const int p0w_u = __builtin_amdgcn_readfirstlane(base + s * 16);

        // ---- scalar loads: pair indices + segment ids for this strip ----
        const int* a2ps = a2p + 2 * p0w_u;
        const int* segs = seg + p0w_u;
        int pi[16], pj[16], sg[16];
        #pragma unroll
        for (int it = 0; it < 16; ++it) {
            pi[it] = a2ps[2*it];
            pj[it] = a2ps[2*it + 1];
            sg[it] = segs[it];
        }

        // ---- pf nt loads FIRST (pinned above the asm burst) ----
        const f32x2* pf2 = (const f32x2*)(pf + (size_t)(p0w_u + m) * FP);
        f32x2 g0 = {0.f,0.f}, g1 = {0.f,0.f}, g2 = {0.f,0.f}, g3 = {0.f,0.f};
        if (q == 0) {
            g0 = __builtin_nontemporal_load(&pf2[0]);
            g1 = __builtin_nontemporal_load(&pf2[1]);
            g2 = __builtin_nontemporal_load(&pf2[2]);
            g3 = __builtin_nontemporal_load(&pf2[3]);
        } else if (q == 1) {
            g0 = __builtin_nontemporal_load(&pf2[4]);
            g1 = __builtin_nontemporal_load(&pf2[5]);
            g2 = __builtin_nontemporal_load(&pf2[6]);
        }
        __builtin_amdgcn_sched_barrier(0);

        // ---- UV8 gather burst: 32 volatile ushort loads, one vmcnt wait ----
        unsigned uvi[16], uvj[16];
        const unsigned lo2 = (unsigned)(lane << 1);
        #pragma unroll
        for (int it = 0; it < 16; ++it) {
            unsigned offi = ((unsigned)pi[it] << 7) | lo2;
            unsigned offj = ((unsigned)pj[it] << 7) | lo2;
            asm volatile("global_load_ushort %0, %1, %2"
                         : "=v"(uvi[it]) : "v"(offi), "s"(UV8));
            asm volatile("global_load_ushort %0, %1, %2"
                         : "=v"(uvj[it]) : "v"(offj), "s"(UV8));
        }

        // single round-trip wait; fence (rule #18)
        asm volatile("s_waitcnt vmcnt(0)" ::: "memory");
        __builtin_amdgcn_sched_barrier(0);

        // ---- APs = relu(U_i+V_j+b) + relu(U_j+V_i+b) -> sX[:,0:50] ----
        #pragma unroll
        for (int it = 0; it < 16; ++it) {
            if (lane < H) {
                float2 fi = unpk_fp8(uvi[it]);   // x=U_i, y=V_i
                float2 fj = unpk_fp8(uvj[it]);   // x=U_j, y=V_j
                float aps = fmaxf(fi.x + fj.y + bap, 0.f) + fmaxf(fj.x + fi.y + bap, 0.f);
                sX[row0 + it][lane] = f2bf1(aps);
            }
        }

        // ---- PP -> sX[:,50:100] (bf16), PA -> regs, one K=32 MFMA pass ----
        short8 afrag = mk8(cvtpk(g0.x, g0.y), cvtpk(g1.x, g1.y),
                           cvtpk(g2.x, g2.y), cvtpk(g3.x, g3.y));
        float pa[4][4];
        {
            const short8* B = (const short8*)W2f;
            #pragma unroll
            for (int tn = 0; tn < 8; ++tn) {
                f32x4 c = {0.f, 0.f, 0.f, 0.f};
                short8 b = B[tn*64 + lane];
                c = __builtin_amdgcn_mfma_f32_16x16x32_bf16(afrag, b, c, 0, 0, 0);
                int col = (tn&3)*16 + m;
                if (tn < 4) {
                    if (col < H) {
                        float bias = b_PP[col];
                        #pragma unroll
                        for (int reg = 0; reg < 4; ++reg)
                            sX[row0 + q*4 + reg][H + col] = f2bf1(fmaxf(c[reg] + bias, 0.f));
                    }
                } else {
                    float bias = (col < H) ? b_PA[col] : 0.f;
                    #pragma unroll
                    for (int reg = 0; reg < 4; ++reg)
                        pa[tn-4][reg] = fmaxf(c[reg] + bias, 0.f);
                }
            }
        }

        // ---- wave-level 16-row segment-sum of PA (seg sorted) ----
        #pragma unroll
        for (int tn4 = 0; tn4 < 4; ++tn4) {
            float v[16];
            #pragma unroll
            for (int g = 0; g < 4; ++g) {
                int src = m + (g << 4);
                #pragma unroll
                for (int r4 = 0; r4 < 4; ++r4)
                    v[g*4 + r4] = __shfl(pa[tn4][r4], src, 64);
            }
            int col = tn4*16 + m;
            if (q == 0 && col < H) {
                float acc = v[0]; int cur = sg[0];
                #pragma unroll
                for (int r = 1; r < 16; ++r) {
                    if (sg[r] != cur) {
                        atomicAdd(&PAsum[(size_t)cur*H + col], acc);
                        acc = 0.f; cur = sg[r];
                    }
                    acc += v[r];
                }
                atomicAdd(&PAsum[(size_t)cur*H + col], acc);
            }
        }

        // wave-local LDS writes must land before fragment reads (wave-sync)
        asm volatile("s_waitcnt lgkmcnt(0)" ::: "memory");
        __builtin_amdgcn_sched_barrier(0);

        // ---- P = relu(X @ W_P + b_P), per-wave M=16 N=64 K=128 ----
        {
            short8 afr[4];
            #pragma unroll
            for (int tk = 0; tk < 4; ++tk)
                afr[tk] = *(const short8*)&sX[row0 + m][tk*32 + q*8];
            const short8* B = (const short8*)WPf;
            f32x4 acc[4];
            #pragma unroll
            for (int tn = 0; tn < 4; ++tn) acc[tn] = (f32x4){0.f, 0.f, 0.f, 0.f};
            #pragma unroll
            for (int tk = 0; tk < 4; ++tk) {
                #pragma unroll
                for (int tn = 0; tn < 4; ++tn) {
                    short8 b = B[(tk*4 + tn)*64 + lane];
                    acc[tn] = __builtin_amdgcn_mfma_f32_16x16x32_bf16(afr[tk], b, acc[tn], 0, 0, 0);
                }
            }
            #pragma unroll
            for (int tn = 0; tn < 4; ++tn) {
                int col = tn*16 + m;
                if (col < H) {
                    float bp = b_P[col];
                    #pragma unroll
                    for (int reg = 0; reg < 4; ++reg) {
                        int row = q*4 + reg;
                        Pout[(size_t)(p0w_u + row)*H + col] = fmaxf(acc[tn][reg] + bp, 0.f);
                    }
                }
            }
        }

        // make strip0's afr ds_reads retire before strip1 rewrites rows
        asm volatile("s_waitcnt lgkmcnt(0)" ::: "memory");
        __builtin_amdgcn_sched_barrier(0);
    }
}

// ---------------------------------------------------------------------------
// K3: A = relu([AAb | PAsum] @ W_A + b_A), 64 atoms/block; nt input loads.
// ---------------------------------------------------------------------------
__global__ __launch_bounds__(256) void k_A(
    const ushort* __restrict__ AAb, const float* __restrict__ PAsum,
    const ushort* __restrict__ WAf, const float* __restrict__ b_A,
    float* __restrict__ Aout)
{
    __shared__ __align__(16) ushort sX[64][136];
    const int t = threadIdx.x, lane = t & 63, w = t >> 6;
    const int a0 = blockIdx.x * 64;
    const int row0 = w * 16;

    for (int idx = t; idx < 64*50; idx += 256) {
        int r = idx / 50, c = idx % 50;
        int rg = a0 + r;
        ushort aa = 0; float ps = 0.f;
        if (rg < NA) {
            aa = __builtin_nontemporal_load(&AAb[(size_t)rg*H + c]);
            ps = __builtin_nontemporal_load(&PAsum[(size_t)rg*H + c]);
        }
        sX[r][c] = aa;
        sX[r][H + c] = f2bf1(ps);
    }
    for (int idx = t; idx < 64*28; idx += 256) {
        int r = idx / 28, c = 100 + idx % 28;
        sX[r][c] = 0;
    }
    __syncthreads();

    short8 afr[4];
    #pragma unroll
    for (int tk = 0; tk < 4; ++tk)
        afr[tk] = *(const short8*)&sX[row0 + (lane&15)][tk*32 + (lane>>4)*8];
    const short8* B = (const short8*)WAf;
    f32x4 acc[4];
    #pragma unroll
    for (int tn = 0; tn < 4; ++tn) acc[tn] = (f32x4){0.f, 0.f, 0.f, 0.f};
    #pragma unroll
    for (int tk = 0; tk < 4; ++tk) {
        #pragma unroll
        for (int tn = 0; tn < 4; ++tn) {
            short8 b = B[(tk*4 + tn)*64 + lane];
            acc[tn] = __builtin_amdgcn_mfma_f32_16x16x32_bf16(afr[tk], b, acc[tn], 0, 0, 0);
        }
    }
    #pragma unroll
    for (int tn = 0; tn < 4; ++tn) {
        int col = tn*16 + (lane&15);
        if (col < H) {
            float ba = b_A[col];
            #pragma unroll
            for (int reg = 0; reg < 4; ++reg) {
                int row = row0 + (lane>>4)*4 + reg;
                int rg = a0 + row;
                if (rg < NA) Aout[(size_t)rg*H + col] = fmaxf(acc[tn][reg] + ba, 0.f);
            }
        }
    }
}

// ---------------------------------------------------------------------------
extern "C" void kernel_launch(void* const* d_in, const int* in_sizes, int n_in,
                              void* d_out, int out_size, void* d_ws, size_t ws_size,
                              hipStream_t stream)
{
    const float* af   = (const float*)d_in[0];
    const float* pf   = (const float*)d_in[1];
    const int*   seg  = (const int*)d_in[2];
    const int*   a2p  = (const int*)d_in[3];
    const float* W_AA = (const float*)d_in[4];
    const float* b_AA = (const float*)d_in[5];
    const float* W_PA = (const float*)d_in[6];
    const float* b_PA = (const float*)d_in[7];
    const float* W_A  = (const float*)d_in[8];
    const float* b_A  = (const float*)d_in[9];
    const float* W_AP = (const float*)d_in[10];
    const float* b_AP = (const float*)d_in[11];
    const float* W_PP = (const float*)d_in[12];
    const float* b_PP = (const float*)d_in[13];
    const float* W_P  = (const float*)d_in[14];
    const float* b_P  = (const float*)d_in[15];

    float* Aout = (float*)d_out;
    float* Pout = (float*)d_out + (size_t)NA * H;

    ushort*   AAb   = (ushort*)d_ws;                         // 5 MB
    float*    PAsum = (float*)(AAb + (size_t)NA * H);        // 10 MB
    ushort*   UV8   = (ushort*)(PAsum + (size_t)NA * H);     // 6.4 MB
    ushort*   WPf   = UV8 + (size_t)NA * 64;                 // 16 KB
    ushort*   WAf   = WPf + 4*4*64*8;                        // 16 KB
    ushort*   W2f   = WAf + 4*4*64*8;                        // 8 KB
    ushort*   WPREf = W2f + 8*64*8;                          // 36 KB

    hipMemsetAsync(PAsum, 0, (size_t)NA * H * sizeof(float), stream);
    k_prep_frags<<<16, 256, 0, stream>>>(W_P, W_A, W_PP, W_PA, W_AA, W_AP,
                                         WPf, WAf, W2f, WPREf);
    k_atom_pre<<<(NA + 63) / 64, 256, 0, stream>>>(af, WPREf, b_AA, AAb, UV8);
    k_pairs<<<(NP + 127) / 128, 256, 0, stream>>>(pf, seg, a2p, UV8,
                                                  b_PP, b_PA, b_AP, b_P,
                                                  WPf, W2f, PAsum, Pout);
    k_A<<<(NA + 63) / 64, 256, 0, stream>>>(AAb, PAsum, WAf, b_A, Aout);
}

// Round 15
// 221.822 us; speedup vs baseline: 1.1482x; 1.0168x over previous
//
#include <hip/hip_runtime.h>
#include <hip/hip_bf16.h>

#define NA 50000
#define NP 1000000
#define FA 75
#define FP 14
#define H  50

typedef __attribute__((ext_vector_type(8))) short short8;
typedef __attribute__((ext_vector_type(4))) float f32x4;
typedef __attribute__((ext_vector_type(2))) float f32x2;

__device__ __forceinline__ ushort f2bf(float f) {
    union { float f; unsigned u; } v; v.f = f;
    unsigned r = v.u + 0x7FFF + ((v.u >> 16) & 1);   // RNE
    return (ushort)(r >> 16);
}
__device__ __forceinline__ unsigned cvtpk(float lo, float hi) {
    unsigned r;
    asm("v_cvt_pk_bf16_f32 %0, %1, %2" : "=v"(r) : "v"(lo), "v"(hi));
    return r;
}
__device__ __forceinline__ ushort f2bf1(float f) { return (ushort)cvtpk(f, f); }
__device__ __forceinline__ unsigned pk_fp8(float u, float v) {
    unsigned r;
    asm("v_cvt_pk_fp8_f32 %0, %1, %2" : "=v"(r) : "v"(u), "v"(v));
    return r;
}
__device__ __forceinline__ float2 unpk_fp8(unsigned w) {
    float2 r;
    asm("v_cvt_pk_f32_fp8 %0, %1" : "=v"(r) : "v"(w));
    return r;
}
__device__ __forceinline__ short8 mk8(unsigned a, unsigned b, unsigned c, unsigned d) {
    union { unsigned u[4]; short8 s; } x; x.u[0]=a; x.u[1]=b; x.u[2]=c; x.u[3]=d; return x.s;
}

// ---------------------------------------------------------------------------
// K0: pack weights into MFMA B-fragment order (bf16), zero-padded.
// B-frag 16x16x32: lane l, elem j -> W[k = tk*32+(l>>4)*8+j][col = tn*16+(l&15)]
// WPf/WAf:  [tk=4][tn=4][64][8]   (K=128 pad from 100, N=64 pad from 50)
// W2f:      [tn=8][64][8]         (K=32 pad from 14; tn 0..3 = W_PP, 4..7 = W_PA)
// WPREf:    [tk=3][tn=12][64][8]  (K=96 pad from 75; N=192: [AA|pad][U|pad][V|pad])
// ---------------------------------------------------------------------------
__global__ __launch_bounds__(256) void k_prep_frags(
    const float* __restrict__ W_P, const float* __restrict__ W_A,
    const float* __restrict__ W_PP, const float* __restrict__ W_PA,
    const float* __restrict__ W_AA, const float* __restrict__ W_AP,
    ushort* __restrict__ WPf, ushort* __restrict__ WAf, ushort* __restrict__ W2f,
    ushort* __restrict__ WPREf)
{
    const int t0 = blockIdx.x * 256 + threadIdx.x;
    const int STR = 16 * 256;
    for (int idx = t0; idx < 4*4*64*8; idx += STR) {
        int j = idx & 7, l = (idx >> 3) & 63, tn = (idx >> 9) & 3, tk = idx >> 11;
        int k = tk*32 + (l>>4)*8 + j;
        int c = tn*16 + (l&15);
        ushort vp = 0, va = 0;
        if (k < 100 && c < 50) { vp = f2bf(W_P[k*50+c]); va = f2bf(W_A[k*50+c]); }
        WPf[idx] = vp; WAf[idx] = va;
    }
    for (int idx = t0; idx < 8*64*8; idx += STR) {
        int j = idx & 7, l = (idx >> 3) & 63, tn = idx >> 9;
        int k = (l>>4)*8 + j;
        int c = (tn&3)*16 + (l&15);
        ushort v = 0;
        if (k < 14 && c < 50) v = f2bf(tn < 4 ? W_PP[k*50+c] : W_PA[k*50+c]);
        W2f[idx] = v;
    }
    for (int idx = t0; idx < 3*12*64*8; idx += STR) {
        int j = idx & 7, l = (idx >> 3) & 63;
        int g = idx >> 9;            // tk*12+tn
        int tn = g % 12, tk = g / 12;
        int k = tk*32 + (l>>4)*8 + j;
        int sn = tn*16 + (l&15);
        int which = sn >> 6, col = sn & 63;
        ushort v = 0;
        if (k < FA && col < H) {
            float w = (which == 0) ? W_AA[k*H+col]
                    : (which == 1) ? W_AP[k*H+col]
                                   : W_AP[(FA+k)*H+col];
            v = f2bf(w);
        }
        WPREf[idx] = v;
    }
}

// ---------------------------------------------------------------------------
// K1: per-atom precompute via MFMA, 64 atoms/block.
//   AAb bf16 [NA][50];  UV8[atom][64] ushort: byte0=fp8(U), byte1=fp8(V).
//   af read via non-temporal loads (read-once stream, no L2 allocate).
// ---------------------------------------------------------------------------
__global__ __launch_bounds__(256) void k_atom_pre(
    const float* __restrict__ af, const ushort* __restrict__ WPREf,
    const float* __restrict__ b_AA,
    ushort* __restrict__ AAb, ushort* __restrict__ UV8)
{
    __shared__ __align__(16) ushort sAF[64][104];
    const int t = threadIdx.x, lane = t & 63, w = t >> 6;
    const int a0 = blockIdx.x * 64, row0 = w * 16;

    for (int idx = t; idx < 64*96; idx += 256) {
        int r = idx / 96, c = idx % 96;
        int ag = a0 + r;
        float v = (c < FA && ag < NA) ? __builtin_nontemporal_load(&af[(size_t)ag*FA + c]) : 0.f;
        sAF[r][c] = f2bf(v);
    }
    __syncthreads();

    short8 afr[3];
    #pragma unroll
    for (int tk = 0; tk < 3; ++tk)
        afr[tk] = *(const short8*)&sAF[row0 + (lane&15)][tk*32 + (lane>>4)*8];

    const short8* B = (const short8*)WPREf;
    f32x4 acc[12];
    #pragma unroll
    for (int tn = 0; tn < 12; ++tn) acc[tn] = (f32x4){0.f, 0.f, 0.f, 0.f};
    #pragma unroll
    for (int tk = 0; tk < 3; ++tk) {
        #pragma unroll
        for (int tn = 0; tn < 12; ++tn) {
            short8 b = B[(tk*12 + tn)*64 + lane];
            acc[tn] = __builtin_amdgcn_mfma_f32_16x16x32_bf16(afr[tk], b, acc[tn], 0, 0, 0);
        }
    }

    #pragma unroll
    for (int tn = 0; tn < 4; ++tn) {
        int col = tn*16 + (lane&15);
        if (col < H) {
            float ba = b_AA[col];
            #pragma unroll
            for (int reg = 0; reg < 4; ++reg) {
                int atom = a0 + row0 + (lane>>4)*4 + reg;
                if (atom < NA) {
                    AAb[(size_t)atom*H + col] = f2bf(fmaxf(acc[tn][reg] + ba, 0.f));
                    UV8[(size_t)atom*64 + col] =
                        (ushort)pk_fp8(acc[4 + tn][reg], acc[8 + tn][reg]);
                }
            }
        }
    }
}

// ---------------------------------------------------------------------------
// K2: 64 pairs/block, 4 waves (proven r9 structure), wave-independent.
//   fp8 UV8 gather burst (32 volatile asm loads, one vmcnt wait); pf via
//   non-temporal loads; PP via K=32 MFMA; PA reg segsum (sorted, ~90
//   atomics/wave); P via 16 MFMA/wave; plain stores (L2 write-coalescing).
// ---------------------------------------------------------------------------
__global__ __launch_bounds__(256, 4) void k_pairs(
    const float* __restrict__ pf, const int* __restrict__ seg, const int* __restrict__ a2p,
    const ushort* __restrict__ UV8,
    const float* __restrict__ b_PP, const float* __restrict__ b_PA,
    const float* __restrict__ b_AP, const float* __restrict__ b_P,
    const ushort* __restrict__ WPf, const ushort* __restrict__ W2f,
    float* __restrict__ PAsum, float* __restrict__ Pout)
{
    __shared__ __align__(16) ushort sX[64][136];    // X bf16: [APs|PP|0pad], K=128

    const int t = threadIdx.x;
    const int w = t >> 6, lane = t & 63;
    const int q = lane >> 4, m = lane & 15;
    const int p0 = blockIdx.x * 64;
    const int row0 = w * 16;
    const int p0w_u = __builtin_amdgcn_readfirstlane(p0 + row0);  // uniform

    // ---- scalar loads: pair indices + segment ids for this wave's 16 pairs ----
    const int* a2ps = a2p + 2 * p0w_u;
    const int* segs = seg + p0w_u;
    int pi[16], pj[16], sg[16];
    #pragma unroll
    for (int it = 0; it < 16; ++it) {
        pi[it] = a2ps[2*it];
        pj[it] = a2ps[2*it + 1];
        sg[it] = segs[it];
    }

    // ---- pf A-frag via NT loads, pinned above the asm burst ----
    const f32x2* pf2 = (const f32x2*)(pf + (size_t)(p0w_u + m) * FP);
    f32x2 g0 = {0.f,0.f}, g1 = {0.f,0.f}, g2 = {0.f,0.f}, g3 = {0.f,0.f};
    if (q == 0) {
        g0 = __builtin_nontemporal_load(&pf2[0]);
        g1 = __builtin_nontemporal_load(&pf2[1]);
        g2 = __builtin_nontemporal_load(&pf2[2]);
        g3 = __builtin_nontemporal_load(&pf2[3]);
    } else if (q == 1) {
        g0 = __builtin_nontemporal_load(&pf2[4]);
        g1 = __builtin_nontemporal_load(&pf2[5]);
        g2 = __builtin_nontemporal_load(&pf2[6]);
    }
    float bap = (lane < H) ? b_AP[lane] : 0.f;
    __builtin_amdgcn_sched_barrier(0);   // pin the above loads before the burst

    // ---- UV8 gather burst: 32 volatile ushort loads, one vmcnt wait ----
    unsigned uvi[16], uvj[16];
    const unsigned lo2 = (unsigned)(lane << 1);
    #pragma unroll
    for (int it = 0; it < 16; ++it) {
        unsigned offi = ((unsigned)pi[it] << 7) | lo2;
        unsigned offj = ((unsigned)pj[it] << 7) | lo2;
        asm volatile("global_load_ushort %0, %1, %2"
                     : "=v"(uvi[it]) : "v"(offi), "s"(UV8));
        asm volatile("global_load_ushort %0, %1, %2"
                     : "=v"(uvj[it]) : "v"(offj), "s"(UV8));
    }

    // zero X K-pad cols 100..127 of own rows (overlaps with loads in flight)
    if (lane < 16) {
        unsigned long long* rowp = (unsigned long long*)&sX[row0 + lane][100];
        #pragma unroll
        for (int d = 0; d < 7; ++d) rowp[d] = 0ull;
    }

    // single round-trip wait; fence so no consumer is hoisted above (rule #18)
    asm volatile("s_waitcnt vmcnt(0)" ::: "memory");
    __builtin_amdgcn_sched_barrier(0);

    // ---- APs = relu(U_i+V_j+b) + relu(U_j+V_i+b) -> sX[:,0:50] ----
    #pragma unroll
    for (int it = 0; it < 16; ++it) {
        if (lane < H) {
            float2 fi = unpk_fp8(uvi[it]);   // x=U_i, y=V_i
            float2 fj = unpk_fp8(uvj[it]);   // x=U_j, y=V_j
            float aps = fmaxf(fi.x + fj.y + bap, 0.f) + fmaxf(fj.x + fi.y + bap, 0.f);
            sX[row0 + it][lane] = f2bf1(aps);
        }
    }

    // ---- PP -> sX[:,50:100] (bf16), PA -> regs, one K=32 MFMA pass ----
    short8 afrag = mk8(cvtpk(g0.x, g0.y), cvtpk(g1.x, g1.y),
                       cvtpk(g2.x, g2.y), cvtpk(g3.x, g3.y));
    float pa[4][4];
    {
        const short8* B = (const short8*)W2f;
        #pragma unroll
        for (int tn = 0; tn < 8; ++tn) {
            f32x4 c = {0.f, 0.f, 0.f, 0.f};
            short8 b = B[tn*64 + lane];
            c = __builtin_amdgcn_mfma_f32_16x16x32_bf16(afrag, b, c, 0, 0, 0);
            int col = (tn&3)*16 + m;
            if (tn < 4) {
                if (col < H) {
                    float bias = b_PP[col];
                    #pragma unroll
                    for (int reg = 0; reg < 4; ++reg)
                        sX[row0 + q*4 + reg][H + col] = f2bf1(fmaxf(c[reg] + bias, 0.f));
                }
            } else {
                float bias = (col < H) ? b_PA[col] : 0.f;
                #pragma unroll
                for (int reg = 0; reg < 4; ++reg)
                    pa[tn-4][reg] = fmaxf(c[reg] + bias, 0.f);
            }
        }
    }

    // ---- wave-level 16-row segment-sum of PA (seg sorted) ----
    #pragma unroll
    for (int tn4 = 0; tn4 < 4; ++tn4) {
        float v[16];
        #pragma unroll
        for (int g = 0; g < 4; ++g) {
            int src = m + (g << 4);
            #pragma unroll
            for (int r4 = 0; r4 < 4; ++r4)
                v[g*4 + r4] = __shfl(pa[tn4][r4], src, 64);
        }
        int col = tn4*16 + m;
        if (q == 0 && col < H) {
            float acc = v[0]; int cur = sg[0];
            #pragma unroll
            for (int r = 1; r < 16; ++r) {
                if (sg[r] != cur) {
                    atomicAdd(&PAsum[(size_t)cur*H + col], acc);
                    acc = 0.f; cur = sg[r];
                }
                acc += v[r];
            }
            atomicAdd(&PAsum[(size_t)cur*H + col], acc);
        }
    }

    // all wave-local LDS writes must land before fragment reads (wave-sync)
    asm volatile("s_waitcnt lgkmcnt(0)" ::: "memory");
    __builtin_amdgcn_sched_barrier(0);

    // ---- P = relu(X @ W_P + b_P), per-wave M=16 N=64 K=128 ----
    {
        short8 afr[4];
        #pragma unroll
        for (int tk = 0; tk < 4; ++tk)
            afr[tk] = *(const short8*)&sX[row0 + m][tk*32 + q*8];
        const short8* B = (const short8*)WPf;
        f32x4 acc[4];
        #pragma unroll
        for (int tn = 0; tn < 4; ++tn) acc[tn] = (f32x4){0.f, 0.f, 0.f, 0.f};
        #pragma unroll
        for (int tk = 0; tk < 4; ++tk) {
            #pragma unroll
            for (int tn = 0; tn < 4; ++tn) {
                short8 b = B[(tk*4 + tn)*64 + lane];
                acc[tn] = __builtin_amdgcn_mfma_f32_16x16x32_bf16(afr[tk], b, acc[tn], 0, 0, 0);
            }
        }
        #pragma unroll
        for (int tn = 0; tn < 4; ++tn) {
            int col = tn*16 + m;
            if (col < H) {
                float bp = b_P[col];
                #pragma unroll
                for (int reg = 0; reg < 4; ++reg) {
                    int row = row0 + q*4 + reg;
                    Pout[(size_t)(p0 + row)*H + col] = fmaxf(acc[tn][reg] + bp, 0.f);
                }
            }
        }
    }
}

// ---------------------------------------------------------------------------
// K3: A = relu([AAb | PAsum] @ W_A + b_A), 64 atoms/block; NT input loads.
// ---------------------------------------------------------------------------
__global__ __launch_bounds__(256) void k_A(
    const ushort* __restrict__ AAb, const float* __restrict__ PAsum,
    const ushort* __restrict__ WAf, const float* __restrict__ b_A,
    float* __restrict__ Aout)
{
    __shared__ __align__(16) ushort sX[64][136];
    const int t = threadIdx.x, lane = t & 63, w = t >> 6;
    const int a0 = blockIdx.x * 64;
    const int row0 = w * 16;

    for (int idx = t; idx < 64*50; idx += 256) {
        int r = idx / 50, c = idx % 50;
        int rg = a0 + r;
        ushort aa = 0; float ps = 0.f;
        if (rg < NA) {
            aa = __builtin_nontemporal_load(&AAb[(size_t)rg*H + c]);
            ps = __builtin_nontemporal_load(&PAsum[(size_t)rg*H + c]);
        }
        sX[r][c] = aa;
        sX[r][H + c] = f2bf1(ps);
    }
    for (int idx = t; idx < 64*28; idx += 256) {
        int r = idx / 28, c = 100 + idx % 28;
        sX[r][c] = 0;
    }
    __syncthreads();

    short8 afr[4];
    #pragma unroll
    for (int tk = 0; tk < 4; ++tk)
        afr[tk] = *(const short8*)&sX[row0 + (lane&15)][tk*32 + (lane>>4)*8];
    const short8* B = (const short8*)WAf;
    f32x4 acc[4];
    #pragma unroll
    for (int tn = 0; tn < 4; ++tn) acc[tn] = (f32x4){0.f, 0.f, 0.f, 0.f};
    #pragma unroll
    for (int tk = 0; tk < 4; ++tk) {
        #pragma unroll
        for (int tn = 0; tn < 4; ++tn) {
            short8 b = B[(tk*4 + tn)*64 + lane];
            acc[tn] = __builtin_amdgcn_mfma_f32_16x16x32_bf16(afr[tk], b, acc[tn], 0, 0, 0);
        }
    }
    #pragma unroll
    for (int tn = 0; tn < 4; ++tn) {
        int col = tn*16 + (lane&15);
        if (col < H) {
            float ba = b_A[col];
            #pragma unroll
            for (int reg = 0; reg < 4; ++reg) {
                int row = row0 + (lane>>4)*4 + reg;
                int rg = a0 + row;
                if (rg < NA) Aout[(size_t)rg*H + col] = fmaxf(acc[tn][reg] + ba, 0.f);
            }
        }
    }
}

// ---------------------------------------------------------------------------
extern "C" void kernel_launch(void* const* d_in, const int* in_sizes, int n_in,
                              void* d_out, int out_size, void* d_ws, size_t ws_size,
                              hipStream_t stream)
{
    const float* af   = (const float*)d_in[0];
    const float* pf   = (const float*)d_in[1];
    const int*   seg  = (const int*)d_in[2];
    const int*   a2p  = (const int*)d_in[3];
    const float* W_AA = (const float*)d_in[4];
    const float* b_AA = (const float*)d_in[5];
    const float* W_PA = (const float*)d_in[6];
    const float* b_PA = (const float*)d_in[7];
    const float* W_A  = (const float*)d_in[8];
    const float* b_A  = (const float*)d_in[9];
    const float* W_AP = (const float*)d_in[10];
    const float* b_AP = (const float*)d_in[11];
    const float* W_PP = (const float*)d_in[12];
    const float* b_PP = (const float*)d_in[13];
    const float* W_P  = (const float*)d_in[14];
    const float* b_P  = (const float*)d_in[15];

    float* Aout = (float*)d_out;
    float* Pout = (float*)d_out + (size_t)NA * H;

    ushort*   AAb   = (ushort*)d_ws;                         // 5 MB
    float*    PAsum = (float*)(AAb + (size_t)NA * H);        // 10 MB
    ushort*   UV8   = (ushort*)(PAsum + (size_t)NA * H);     // 6.4 MB
    ushort*   WPf   = UV8 + (size_t)NA * 64;                 // 16 KB
    ushort*   WAf   = WPf + 4*4*64*8;                        // 16 KB
    ushort*   W2f   = WAf + 4*4*64*8;                        // 8 KB
    ushort*   WPREf = W2f + 8*64*8;                          // 36 KB

    hipMemsetAsync(PAsum, 0, (size_t)NA * H * sizeof(float), stream);
    k_prep_frags<<<16, 256, 0, stream>>>(W_P, W_A, W_PP, W_PA, W_AA, W_AP,
                                         WPf, WAf, W2f, WPREf);
    k_atom_pre<<<(NA + 63) / 64, 256, 0, stream>>>(af, WPREf, b_AA, AAb, UV8);
    k_pairs<<<NP / 64, 256, 0, stream>>>(pf, seg, a2p, UV8, b_PP, b_PA, b_AP, b_P,
                                         WPf, W2f, PAsum, Pout);
    k_A<<<(NA + 63) / 64, 256, 0, stream>>>(AAb, PAsum, WAf, b_A, Aout);
}

// Round 16
// 210.721 us; speedup vs baseline: 1.2087x; 1.0527x over previous
//
#include <hip/hip_runtime.h>
#include <hip/hip_bf16.h>

#define NA 50000
#define NP 1000000
#define FA 75
#define FP 14
#define H  50

typedef __attribute__((ext_vector_type(8))) short short8;
typedef __attribute__((ext_vector_type(4))) float f32x4;

__device__ __forceinline__ ushort f2bf(float f) {
    union { float f; unsigned u; } v; v.f = f;
    unsigned r = v.u + 0x7FFF + ((v.u >> 16) & 1);   // RNE
    return (ushort)(r >> 16);
}
__device__ __forceinline__ unsigned cvtpk(float lo, float hi) {
    unsigned r;
    asm("v_cvt_pk_bf16_f32 %0, %1, %2" : "=v"(r) : "v"(lo), "v"(hi));
    return r;
}
__device__ __forceinline__ ushort f2bf1(float f) { return (ushort)cvtpk(f, f); }
__device__ __forceinline__ unsigned pk_fp8(float u, float v) {
    unsigned r;
    asm("v_cvt_pk_fp8_f32 %0, %1, %2" : "=v"(r) : "v"(u), "v"(v));
    return r;                                  // byte0 = fp8(u), byte1 = fp8(v)
}
__device__ __forceinline__ float2 unpk_fp8(unsigned w) {
    float2 r;
    asm("v_cvt_pk_f32_fp8 %0, %1" : "=v"(r) : "v"(w));
    return r;                                  // r.x = byte0, r.y = byte1
}
__device__ __forceinline__ short8 mk8(unsigned a, unsigned b, unsigned c, unsigned d) {
    union { unsigned u[4]; short8 s; } x; x.u[0]=a; x.u[1]=b; x.u[2]=c; x.u[3]=d; return x.s;
}

// ---------------------------------------------------------------------------
// K0: pack weights into MFMA B-fragment order (bf16), zero-padded.
// B-frag 16x16x32: lane l, elem j -> W[k = tk*32+(l>>4)*8+j][col = tn*16+(l&15)]
// WPf/WAf:  [tk=4][tn=4][64][8]   (K=128 pad from 100, N=64 pad from 50)
// W2f:      [tn=8][64][8]         (K=32 pad from 14; tn 0..3 = W_PP, 4..7 = W_PA)
// WPREf:    [tk=3][tn=12][64][8]  (K=96 pad from 75; N=192: [AA|pad][U|pad][V|pad])
// ---------------------------------------------------------------------------
__global__ __launch_bounds__(256) void k_prep_frags(
    const float* __restrict__ W_P, const float* __restrict__ W_A,
    const float* __restrict__ W_PP, const float* __restrict__ W_PA,
    const float* __restrict__ W_AA, const float* __restrict__ W_AP,
    ushort* __restrict__ WPf, ushort* __restrict__ WAf, ushort* __restrict__ W2f,
    ushort* __restrict__ WPREf)
{
    const int t0 = blockIdx.x * 256 + threadIdx.x;
    const int STR = 16 * 256;
    for (int idx = t0; idx < 4*4*64*8; idx += STR) {
        int j = idx & 7, l = (idx >> 3) & 63, tn = (idx >> 9) & 3, tk = idx >> 11;
        int k = tk*32 + (l>>4)*8 + j;
        int c = tn*16 + (l&15);
        ushort vp = 0, va = 0;
        if (k < 100 && c < 50) { vp = f2bf(W_P[k*50+c]); va = f2bf(W_A[k*50+c]); }
        WPf[idx] = vp; WAf[idx] = va;
    }
    for (int idx = t0; idx < 8*64*8; idx += STR) {
        int j = idx & 7, l = (idx >> 3) & 63, tn = idx >> 9;
        int k = (l>>4)*8 + j;
        int c = (tn&3)*16 + (l&15);
        ushort v = 0;
        if (k < 14 && c < 50) v = f2bf(tn < 4 ? W_PP[k*50+c] : W_PA[k*50+c]);
        W2f[idx] = v;
    }
    for (int idx = t0; idx < 3*12*64*8; idx += STR) {
        int j = idx & 7, l = (idx >> 3) & 63;
        int g = idx >> 9;            // tk*12+tn
        int tn = g % 12, tk = g / 12;
        int k = tk*32 + (l>>4)*8 + j;
        int sn = tn*16 + (l&15);
        int which = sn >> 6, col = sn & 63;
        ushort v = 0;
        if (k < FA && col < H) {
            float w = (which == 0) ? W_AA[k*H+col]
                    : (which == 1) ? W_AP[k*H+col]
                                   : W_AP[(FA+k)*H+col];
            v = f2bf(w);
        }
        WPREf[idx] = v;
    }
}

// ---------------------------------------------------------------------------
// K1: per-atom precompute via MFMA, 64 atoms/block.
//   [AAb | U | V] = af @ [W_AA | W_AP_u | W_AP_v]  (M=64, K=96, N=192)
//   AAb bf16 [NA][50];  UV8[atom][64] ushort: byte0=fp8(U), byte1=fp8(V).
// ---------------------------------------------------------------------------
__global__ __launch_bounds__(256) void k_atom_pre(
    const float* __restrict__ af, const ushort* __restrict__ WPREf,
    const float* __restrict__ b_AA,
    ushort* __restrict__ AAb, ushort* __restrict__ UV8)
{
    __shared__ __align__(16) ushort sAF[64][104];   // bf16 af rows, K-pad to 96
    const int t = threadIdx.x, lane = t & 63, w = t >> 6;
    const int a0 = blockIdx.x * 64, row0 = w * 16;

    for (int idx = t; idx < 64*96; idx += 256) {
        int r = idx / 96, c = idx % 96;
        int ag = a0 + r;
        float v = (c < FA && ag < NA) ? af[(size_t)ag*FA + c] : 0.f;
        sAF[r][c] = f2bf(v);
    }
    __syncthreads();

    short8 afr[3];
    #pragma unroll
    for (int tk = 0; tk < 3; ++tk)
        afr[tk] = *(const short8*)&sAF[row0 + (lane&15)][tk*32 + (lane>>4)*8];

    const short8* B = (const short8*)WPREf;
    f32x4 acc[12];
    #pragma unroll
    for (int tn = 0; tn < 12; ++tn) acc[tn] = (f32x4){0.f, 0.f, 0.f, 0.f};
    #pragma unroll
    for (int tk = 0; tk < 3; ++tk) {
        #pragma unroll
        for (int tn = 0; tn < 12; ++tn) {
            short8 b = B[(tk*12 + tn)*64 + lane];
            acc[tn] = __builtin_amdgcn_mfma_f32_16x16x32_bf16(afr[tk], b, acc[tn], 0, 0, 0);
        }
    }

    #pragma unroll
    for (int tn = 0; tn < 4; ++tn) {
        int col = tn*16 + (lane&15);
        if (col < H) {
            float ba = b_AA[col];
            #pragma unroll
            for (int reg = 0; reg < 4; ++reg) {
                int atom = a0 + row0 + (lane>>4)*4 + reg;
                if (atom < NA) {
                    AAb[(size_t)atom*H + col] = f2bf(fmaxf(acc[tn][reg] + ba, 0.f));
                    UV8[(size_t)atom*64 + col] =
                        (ushort)pk_fp8(acc[4 + tn][reg], acc[8 + tn][reg]);
                }
            }
        }
    }
}

// ---------------------------------------------------------------------------
// K2: 64 pairs/block, 4 waves, wave-independent (no __syncthreads).
//   32 UV8 row-gathers (128B rows, fp8 pairs) as inline-asm burst ->
//   one vmcnt(0) per wave. PP via K=32 MFMA; PA in regs -> wave segsum;
//   P via 16 MFMA/wave.
// ---------------------------------------------------------------------------
__global__ __launch_bounds__(256, 4) void k_pairs(
    const float* __restrict__ pf, const int* __restrict__ seg, const int* __restrict__ a2p,
    const ushort* __restrict__ UV8,
    const float* __restrict__ b_PP, const float* __restrict__ b_PA,
    const float* __restrict__ b_AP, const float* __restrict__ b_P,
    const ushort* __restrict__ WPf, const ushort* __restrict__ W2f,
    float* __restrict__ PAsum, float* __restrict__ Pout)
{
    __shared__ __align__(16) ushort sX[64][136];    // X bf16: [APs|PP|0pad], K=128

    const int t = threadIdx.x;
    const int w = t >> 6, lane = t & 63;
    const int q = lane >> 4, m = lane & 15;
    const int p0 = blockIdx.x * 64;
    const int row0 = w * 16;
    const int p0w_u = __builtin_amdgcn_readfirstlane(p0 + row0);  // uniform

    // ---- scalar loads: pair indices + segment ids for this wave's 16 pairs ----
    const int* a2ps = a2p + 2 * p0w_u;
    const int* segs = seg + p0w_u;
    int pi[16], pj[16], sg[16];
    #pragma unroll
    for (int it = 0; it < 16; ++it) {
        pi[it] = a2ps[2*it];
        pj[it] = a2ps[2*it + 1];
        sg[it] = segs[it];
    }

    // ---- pf A-frag: k = q*8+j, only q<2 carries data (k<14); convert now ----
    const float2* pf2 = (const float2*)(pf + (size_t)(p0w_u + m) * FP);
    float2 g0 = {0.f,0.f}, g1 = {0.f,0.f}, g2 = {0.f,0.f}, g3 = {0.f,0.f};
    if (q == 0)      { g0 = pf2[0]; g1 = pf2[1]; g2 = pf2[2]; g3 = pf2[3]; }  // k0..7
    else if (q == 1) { g0 = pf2[4]; g1 = pf2[5]; g2 = pf2[6]; }               // k8..13
    short8 afrag = mk8(cvtpk(g0.x, g0.y), cvtpk(g1.x, g1.y),
                       cvtpk(g2.x, g2.y), cvtpk(g3.x, g3.y));

    // ---- UV8 gather burst: 32 volatile ushort loads, one vmcnt wait.
    // Rows are 128B; lanes 50-63 read in-row junk (same lines, unused).
    unsigned uvi[16], uvj[16];
    const unsigned lo2 = (unsigned)(lane << 1);
    #pragma unroll
    for (int it = 0; it < 16; ++it) {
        unsigned offi = ((unsigned)pi[it] << 7) | lo2;
        unsigned offj = ((unsigned)pj[it] << 7) | lo2;
        asm volatile("global_load_ushort %0, %1, %2"
                     : "=v"(uvi[it]) : "v"(offi), "s"(UV8));
        asm volatile("global_load_ushort %0, %1, %2"
                     : "=v"(uvj[it]) : "v"(offj), "s"(UV8));
    }

    // zero X K-pad cols 100..127 of own rows (overlaps with loads in flight)
    if (lane < 16) {
        unsigned long long* rowp = (unsigned long long*)&sX[row0 + lane][100];
        #pragma unroll
        for (int d = 0; d < 7; ++d) rowp[d] = 0ull;
    }
    float bap = (lane < H) ? b_AP[lane] : 0.f;

    // single round-trip wait; fence so no consumer is hoisted above (rule #18)
    asm volatile("s_waitcnt vmcnt(0)" ::: "memory");
    __builtin_amdgcn_sched_barrier(0);

    // ---- APs = relu(U_i+V_j+b) + relu(U_j+V_i+b) -> sX[:,0:50] ----
    #pragma unroll
    for (int it = 0; it < 16; ++it) {
        if (lane < H) {
            float2 fi = unpk_fp8(uvi[it]);   // x=U_i, y=V_i
            float2 fj = unpk_fp8(uvj[it]);   // x=U_j, y=V_j
            float aps = fmaxf(fi.x + fj.y + bap, 0.f) + fmaxf(fj.x + fi.y + bap, 0.f);
            sX[row0 + it][lane] = f2bf1(aps);
        }
    }

    // ---- PP -> sX[:,50:100] (bf16), PA -> regs, one K=32 MFMA pass ----
    float pa[4][4];
    {
        const short8* B = (const short8*)W2f;
        #pragma unroll
        for (int tn = 0; tn < 8; ++tn) {
            f32x4 c = {0.f, 0.f, 0.f, 0.f};
            short8 b = B[tn*64 + lane];
            c = __builtin_amdgcn_mfma_f32_16x16x32_bf16(afrag, b, c, 0, 0, 0);
            int col = (tn&3)*16 + m;
            if (tn < 4) {
                if (col < H) {
                    float bias = b_PP[col];
                    #pragma unroll
                    for (int reg = 0; reg < 4; ++reg)
                        sX[row0 + q*4 + reg][H + col] = f2bf1(fmaxf(c[reg] + bias, 0.f));
                }
            } else {
                float bias = (col < H) ? b_PA[col] : 0.f;
                #pragma unroll
                for (int reg = 0; reg < 4; ++reg)
                    pa[tn-4][reg] = fmaxf(c[reg] + bias, 0.f);
            }
        }
    }

    // ---- wave-level 16-row segment-sum of PA (seg sorted) ----
    #pragma unroll
    for (int tn4 = 0; tn4 < 4; ++tn4) {
        float v[16];
        #pragma unroll
        for (int g = 0; g < 4; ++g) {
            int src = m + (g << 4);
            #pragma unroll
            for (int r4 = 0; r4 < 4; ++r4)
                v[g*4 + r4] = __shfl(pa[tn4][r4], src, 64);
        }
        int col = tn4*16 + m;
        if (q == 0 && col < H) {
            float acc = v[0]; int cur = sg[0];
            #pragma unroll
            for (int r = 1; r < 16; ++r) {
                if (sg[r] != cur) {
                    atomicAdd(&PAsum[(size_t)cur*H + col], acc);
                    acc = 0.f; cur = sg[r];
                }
                acc += v[r];
            }
            atomicAdd(&PAsum[(size_t)cur*H + col], acc);
        }
    }

    // all wave-local LDS writes must land before fragment reads (wave-sync)
    asm volatile("s_waitcnt lgkmcnt(0)" ::: "memory");
    __builtin_amdgcn_sched_barrier(0);

    // ---- P = relu(X @ W_P + b_P), per-wave M=16 N=64 K=128 ----
    {
        short8 afr[4];
        #pragma unroll
        for (int tk = 0; tk < 4; ++tk)
            afr[tk] = *(const short8*)&sX[row0 + m][tk*32 + q*8];
        const short8* B = (const short8*)WPf;
        f32x4 acc[4];
        #pragma unroll
        for (int tn = 0; tn < 4; ++tn) acc[tn] = (f32x4){0.f, 0.f, 0.f, 0.f};
        #pragma unroll
        for (int tk = 0; tk < 4; ++tk) {
            #pragma unroll
            for (int tn = 0; tn < 4; ++tn) {
                short8 b = B[(tk*4 + tn)*64 + lane];
                acc[tn] = __builtin_amdgcn_mfma_f32_16x16x32_bf16(afr[tk], b, acc[tn], 0, 0, 0);
            }
        }
        #pragma unroll
        for (int tn = 0; tn < 4; ++tn) {
            int col = tn*16 + m;
            if (col < H) {
                float bp = b_P[col];
                #pragma unroll
                for (int reg = 0; reg < 4; ++reg) {
                    int row = row0 + q*4 + reg;
                    Pout[(size_t)(p0 + row)*H + col] = fmaxf(acc[tn][reg] + bp, 0.f);
                }
            }
        }
    }
}

// ---------------------------------------------------------------------------
// K3: A = relu([AAb | PAsum] @ W_A + b_A), 64 atoms/block.
// ---------------------------------------------------------------------------
__global__ __launch_bounds__(256) void k_A(
    const ushort* __restrict__ AAb, const float* __restrict__ PAsum,
    const ushort* __restrict__ WAf, const float* __restrict__ b_A,
    float* __restrict__ Aout)
{
    __shared__ __align__(16) ushort sX[64][136];
    const int t = threadIdx.x, lane = t & 63, w = t >> 6;
    const int a0 = blockIdx.x * 64;
    const int row0 = w * 16;

    for (int idx = t; idx < 64*50; idx += 256) {
        int r = idx / 50, c = idx % 50;
        int rg = a0 + r;
        ushort aa = 0; float ps = 0.f;
        if (rg < NA) { aa = AAb[(size_t)rg*H + c]; ps = PAsum[(size_t)rg*H + c]; }
        sX[r][c] = aa;
        sX[r][H + c] = f2bf1(ps);
    }
    for (int idx = t; idx < 64*28; idx += 256) {
        int r = idx / 28, c = 100 + idx % 28;
        sX[r][c] = 0;
    }
    __syncthreads();

    short8 afr[4];
    #pragma unroll
    for (int tk = 0; tk < 4; ++tk)
        afr[tk] = *(const short8*)&sX[row0 + (lane&15)][tk*32 + (lane>>4)*8];
    const short8* B = (const short8*)WAf;
    f32x4 acc[4];
    #pragma unroll
    for (int tn = 0; tn < 4; ++tn) acc[tn] = (f32x4){0.f, 0.f, 0.f, 0.f};
    #pragma unroll
    for (int tk = 0; tk < 4; ++tk) {
        #pragma unroll
        for (int tn = 0; tn < 4; ++tn) {
            short8 b = B[(tk*4 + tn)*64 + lane];
            acc[tn] = __builtin_amdgcn_mfma_f32_16x16x32_bf16(afr[tk], b, acc[tn], 0, 0, 0);
        }
    }
    #pragma unroll
    for (int tn = 0; tn < 4; ++tn) {
        int col = tn*16 + (lane&15);
        if (col < H) {
            float ba = b_A[col];
            #pragma unroll
            for (int reg = 0; reg < 4; ++reg) {
                int row = row0 + (lane>>4)*4 + reg;
                int rg = a0 + row;
                if (rg < NA) Aout[(size_t)rg*H + col] = fmaxf(acc[tn][reg] + ba, 0.f);
            }
        }
    }
}

// ---------------------------------------------------------------------------
extern "C" void kernel_launch(void* const* d_in, const int* in_sizes, int n_in,
                              void* d_out, int out_size, void* d_ws, size_t ws_size,
                              hipStream_t stream)
{
    const float* af   = (const float*)d_in[0];
    const float* pf   = (const float*)d_in[1];
    const int*   seg  = (const int*)d_in[2];
    const int*   a2p  = (const int*)d_in[3];
    const float* W_AA = (const float*)d_in[4];
    const float* b_AA = (const float*)d_in[5];
    const float* W_PA = (const float*)d_in[6];
    const float* b_PA = (const float*)d_in[7];
    const float* W_A  = (const float*)d_in[8];
    const float* b_A  = (const float*)d_in[9];
    const float* W_AP = (const float*)d_in[10];
    const float* b_AP = (const float*)d_in[11];
    const float* W_PP = (const float*)d_in[12];
    const float* b_PP = (const float*)d_in[13];
    const float* W_P  = (const float*)d_in[14];
    const float* b_P  = (const float*)d_in[15];

    float* Aout = (float*)d_out;
    float* Pout = (float*)d_out + (size_t)NA * H;

    ushort*   AAb   = (ushort*)d_ws;                         // 5 MB
    float*    PAsum = (float*)(AAb + (size_t)NA * H);        // 10 MB
    ushort*   UV8   = (ushort*)(PAsum + (size_t)NA * H);     // 6.4 MB
    ushort*   WPf   = UV8 + (size_t)NA * 64;                 // 16 KB
    ushort*   WAf   = WPf + 4*4*64*8;                        // 16 KB
    ushort*   W2f   = WAf + 4*4*64*8;                        // 8 KB
    ushort*   WPREf = W2f + 8*64*8;                          // 36 KB

    hipMemsetAsync(PAsum, 0, (size_t)NA * H * sizeof(float), stream);
    k_prep_frags<<<16, 256, 0, stream>>>(W_P, W_A, W_PP, W_PA, W_AA, W_AP,
                                         WPf, WAf, W2f, WPREf);
    k_atom_pre<<<(NA + 63) / 64, 256, 0, stream>>>(af, WPREf, b_AA, AAb, UV8);
    k_pairs<<<NP / 64, 256, 0, stream>>>(pf, seg, a2p, UV8, b_PP, b_PA, b_AP, b_P,
                                         WPf, W2f, PAsum, Pout);
    k_A<<<(NA + 63) / 64, 256, 0, stream>>>(AAb, PAsum, WAf, b_A, Aout);
}